// Round 5
// baseline (664.568 us; speedup 1.0000x reference)
//
#include <hip/hip_runtime.h>

typedef _Float16 f16x8 __attribute__((ext_vector_type(8)));
typedef _Float16 f16x4 __attribute__((ext_vector_type(4)));
typedef _Float16 f16x2 __attribute__((ext_vector_type(2)));
typedef float f32x4 __attribute__((ext_vector_type(4)));

#define NB_   8
#define NN_   2000
#define TT_   64
#define FF_   32
#define HH_   128
#define EE_   32000
#define KD    160        // F + H
#define RSTR  192        // swizzled LDS row stride (f16 elems)
#define NODES 32         // nodes per block
#define BUFE  (NODES * RSTR)   // one activation buffer (elems)

__device__ __forceinline__ float fexp2(float v) { return __builtin_amdgcn_exp2f(v); }
__device__ __forceinline__ float frcp(float v)  { return __builtin_amdgcn_rcpf(v); }

// ---- prep: pack pre-scaled [Wih|Whh] -> fp16 [512][160], gcn_W^T -> fp16, bias, deg=0
// gate rows i,f,o: * -1.44269504 ; g rows [256,384): * -2.88539008
__global__ void prep_kernel(const float* __restrict__ Wih, const float* __restrict__ Whh,
                            const float* __restrict__ bih, const float* __restrict__ bhh,
                            const float* __restrict__ gcnW,
                            _Float16* __restrict__ W16, _Float16* __restrict__ Wg16,
                            float* __restrict__ bias, float* __restrict__ deg) {
  int idx = blockIdx.x * 256 + threadIdx.x;
  if (idx < 512 * KD) {
    int col = idx / KD, k = idx % KD;
    float v = (k < 32) ? Wih[col * 32 + k] : Whh[col * 128 + (k - 32)];
    float sc = (col >= 256 && col < 384) ? -2.88539008f : -1.44269504f;
    W16[idx] = (_Float16)(v * sc);
  } else if (idx < 512 * KD + 128 * 128) {
    int i2 = idx - 512 * KD;
    int colg = i2 >> 7, k = i2 & 127;
    Wg16[i2] = (_Float16)gcnW[k * 128 + colg];   // Wg16[c][k] = gcnW[k][c]
  } else if (idx < 512 * KD + 128 * 128 + 512) {
    int i3 = idx - (512 * KD + 128 * 128);
    float sc = (i3 >= 256 && i3 < 384) ? -2.88539008f : -1.44269504f;
    bias[i3] = (bih[i3] + bhh[i3]) * sc;
  } else if (idx < 512 * KD + 128 * 128 + 512 + NN_) {
    deg[idx - (512 * KD + 128 * 128 + 512)] = 0.f;
  }
}

__global__ void deg_kernel(const int* __restrict__ ei, float* __restrict__ deg) {
  int e = blockIdx.x * 256 + threadIdx.x;
  if (e < EE_ + NN_) {
    int d = (e < EE_) ? ei[EE_ + e] : (e - EE_);
    atomicAdd(&deg[d], 1.f);
  }
}

// ---- exclusive scan of (deg-1) + dinv, one block
__global__ void scan_kernel(const float* __restrict__ deg, int* __restrict__ offs,
                            int* __restrict__ cursor, float* __restrict__ dinv) {
  __shared__ int s0[2048], s1[2048];
  int t = threadIdx.x;
  for (int i = t; i < 2048; i += 1024) s0[i] = (i < NN_) ? ((int)deg[i] - 1) : 0;
  __syncthreads();
  int* src = s0; int* dst = s1;
  for (int off = 1; off < 2048; off <<= 1) {
    for (int i = t; i < 2048; i += 1024)
      dst[i] = src[i] + ((i >= off) ? src[i - off] : 0);
    __syncthreads();
    int* tmp = src; src = dst; dst = tmp;
  }
  for (int i = t; i < NN_; i += 1024) {
    int exc = src[i] - ((int)deg[i] - 1);
    offs[i] = exc;
    cursor[i] = exc;
    float d = deg[i];
    dinv[i] = (d > 0.f) ? __builtin_amdgcn_rsqf(d) : 0.f;
  }
}

__global__ void fill_kernel(const int* __restrict__ ei, const float* __restrict__ dinv,
                            int* __restrict__ cursor, int* __restrict__ csr_src,
                            float* __restrict__ csr_w) {
  int e = blockIdx.x * 256 + threadIdx.x;
  if (e >= EE_) return;
  int s = ei[e], d = ei[EE_ + e];
  int pos = atomicAdd(&cursor[d], 1);
  csr_src[pos] = s;
  csr_w[pos] = dinv[s] * dinv[d];
}

// ---- fused LSTM + GCN-GEMM. 500 blocks x 512 thr, 32 nodes/block.
// Double-buffered activation tile (XOR-swizzled): step t reads buf[t&1], gates write
// h(t+1)/x(t+1) to buf[(t+1)&1] -> ONE barrier per step. All weights + bias in VGPRs;
// bias enters as the C operand of the kc=0 MFMA (no acc init).
__global__ __launch_bounds__(512, 4) void lstm_gcn_kernel(
    const float* __restrict__ x, const _Float16* __restrict__ W16,
    const float* __restrict__ bias, const _Float16* __restrict__ Wg16,
    float* __restrict__ xwT) {
  __shared__ _Float16 A[2 * BUFE];          // 24576 B
  const int tid  = threadIdx.x;
  const int wave = tid >> 6;
  const int lane = tid & 63;
  const int n15  = lane & 15;
  const int q    = lane >> 4;
  const int m    = n15 & 7;
  const int hm   = m >> 2;
  const int qx   = q ^ (m & 3);
  const int node0 = blockIdx.x * NODES;

  // weight A-frags (rows = gate dims g*128+wave*16+n15), pre-scaled; bias f32
  f16x8 Af[4][5];
  f32x4 bt[4];
#pragma unroll
  for (int g = 0; g < 4; ++g) {
    const int row = g * 128 + wave * 16 + n15;
#pragma unroll
    for (int kc = 0; kc < 5; ++kc)
      Af[g][kc] = *(const f16x8*)(W16 + row * KD + kc * 32 + q * 8);
    bt[g] = *(const f32x4*)(bias + g * 128 + wave * 16 + q * 4);
  }

  // per-lane LDS offsets (XOR swizzle: elem(row,k) = row*192 + (((k>>3)^(row&7))<<3) + (k&7))
  const int bRow = n15 * RSTR + (qx << 3);   // + ((kc^hm)<<5) + nt*16*RSTR
  const int hOff = n15 * RSTR + (((4 + 2 * wave + (q >> 1)) ^ m) << 3) + ((q & 1) << 2);

  // x staging: thread stages 2 floats of one node-row per step
  const int xrow = tid >> 4;          // 0..31
  const int xf   = (tid & 15) * 2;
  const int xOff = xrow * RSTR + (((xf >> 3) ^ (xrow & 7)) << 3) + (xf & 7);
  const float* xb = x + (size_t)(node0 + xrow) * (TT_ * FF_) + xf;

  // buf0: h = 0, x(0)
  {
    int row = tid >> 4, ci = tid & 15;
    f16x8 z8 = {(_Float16)0, (_Float16)0, (_Float16)0, (_Float16)0,
                (_Float16)0, (_Float16)0, (_Float16)0, (_Float16)0};
    *(f16x8*)(A + row * RSTR + (((4 + ci) ^ (row & 7)) << 3)) = z8;
    float2 v = *(const float2*)xb;
    f16x2 p = {(_Float16)v.x, (_Float16)v.y};
    *(f16x2*)(A + xOff) = p;
  }
  __syncthreads();

  f32x4 c[2];
  c[0] = (f32x4){0, 0, 0, 0};
  c[1] = (f32x4){0, 0, 0, 0};

  for (int t = 0; t < TT_; ++t) {
    const _Float16* src = A + (t & 1) * BUFE;
    _Float16*       dst = A + ((t + 1) & 1) * BUFE;
    const bool more = (t + 1 < TT_);
    float2 xv;
    if (more) xv = *(const float2*)(xb + (t + 1) * FF_);

    // ---- MFMA phase: z = W·[x;h] + bias (bias via C operand on kc=0)
    f32x4 acc[2][4];
    {
      f16x8 bf0[2];
#pragma unroll
      for (int nt = 0; nt < 2; ++nt)
        bf0[nt] = *(const f16x8*)(src + nt * (16 * RSTR) + bRow + (hm << 5));
#pragma unroll
      for (int nt = 0; nt < 2; ++nt)
#pragma unroll
        for (int g = 0; g < 4; ++g)
          acc[nt][g] = __builtin_amdgcn_mfma_f32_16x16x32_f16(Af[g][0], bf0[nt], bt[g], 0, 0, 0);
#pragma unroll
      for (int kc = 1; kc < 5; ++kc)
#pragma unroll
        for (int nt = 0; nt < 2; ++nt) {
          f16x8 bf = *(const f16x8*)(src + nt * (16 * RSTR) + bRow + ((kc ^ hm) << 5));
#pragma unroll
          for (int g = 0; g < 4; ++g)
            acc[nt][g] = __builtin_amdgcn_mfma_f32_16x16x32_f16(Af[g][kc], bf, acc[nt][g], 0, 0, 0);
        }
    }

    // ---- gates phase: write h(t+1), x(t+1) to the OTHER buffer (no race with src readers)
#pragma unroll
    for (int nt = 0; nt < 2; ++nt) {
      f16x4 hp;
#pragma unroll
      for (int r = 0; r < 4; ++r) {
        float si = frcp(1.f + fexp2(acc[nt][0][r]));
        float sf = frcp(1.f + fexp2(acc[nt][1][r]));
        float tg = 2.f * frcp(1.f + fexp2(acc[nt][2][r])) - 1.f;
        float so = frcp(1.f + fexp2(acc[nt][3][r]));
        float cn = sf * c[nt][r] + si * tg;
        c[nt][r] = cn;
        float tc = 2.f * frcp(1.f + fexp2(-2.88539008f * cn)) - 1.f;
        hp[r] = (_Float16)(so * tc);
      }
      *(f16x4*)(dst + nt * (16 * RSTR) + hOff) = hp;
    }
    if (more) { f16x2 p = {(_Float16)xv.x, (_Float16)xv.y}; *(f16x2*)(dst + xOff) = p; }
    __syncthreads();
  }

  // ---- epilogue: h(T) is in buf0. xwT[n*1024 + col*8 + b] = (h @ gcnW)[node][col]
  f16x8 Ag[4];
#pragma unroll
  for (int kc = 0; kc < 4; ++kc)
    Ag[kc] = *(const f16x8*)(Wg16 + (wave * 16 + n15) * HH_ + kc * 32 + q * 8);
  f32x4 acc2[2];
  acc2[0] = (f32x4){0, 0, 0, 0};
  acc2[1] = (f32x4){0, 0, 0, 0};
#pragma unroll
  for (int kc = 0; kc < 4; ++kc)
#pragma unroll
    for (int nt = 0; nt < 2; ++nt) {
      f16x8 bf = *(const f16x8*)(A + nt * (16 * RSTR) + bRow + (((kc + 1) ^ hm) << 5));
      acc2[nt] = __builtin_amdgcn_mfma_f32_16x16x32_f16(Ag[kc], bf, acc2[nt], 0, 0, 0);
    }
#pragma unroll
  for (int nt = 0; nt < 2; ++nt) {
    int mnode = node0 + nt * 16 + n15;
    int b = mnode / NN_;
    int n = mnode - b * NN_;
    float* o = xwT + (size_t)n * 1024 + (wave * 16 + q * 4) * 8 + b;
    o[0]  = acc2[nt][0];
    o[8]  = acc2[nt][1];
    o[16] = acc2[nt][2];
    o[24] = acc2[nt][3];
  }
}

// ---- fused CSR gather + MLP head: block per dst; xwT is [node][dim][batch] -> one
// float4 (4 batches) per edge per thread, 4-edge unroll (16 loads in flight)
__global__ __launch_bounds__(256) void gathermlp_kernel(
    const float* __restrict__ xwT, const int* __restrict__ offs,
    const float* __restrict__ deg, const float* __restrict__ dinv,
    const int* __restrict__ csr_src, const float* __restrict__ csr_w,
    const float* __restrict__ gcnb,
    const float* __restrict__ W1, const float* __restrict__ b1,
    const float* __restrict__ W2, const float* __restrict__ b2,
    float* __restrict__ out) {
  __shared__ float aggs[8][128];
  __shared__ float W1T[64][132];            // W1T[j][k] = W1[k*64+j]
  const int d = blockIdx.x;
  const int tid = threadIdx.x;
  for (int i = tid; i < 8192; i += 256) W1T[i & 63][i >> 6] = W1[i];
  {
    const int j  = tid & 127;               // dim
    const int bh = tid >> 7;                // batch-half: batches bh*4..bh*4+3
    const int beg = offs[d];
    const int cnt = (int)deg[d] - 1;
    const float* base = xwT + j * 8 + bh * 4;
    f32x4 a = (f32x4){0, 0, 0, 0};
    int e = 0;
    for (; e + 3 < cnt; e += 4) {
      int   s0 = csr_src[beg + e],     s1 = csr_src[beg + e + 1];
      int   s2 = csr_src[beg + e + 2], s3 = csr_src[beg + e + 3];
      float w0 = csr_w[beg + e],       w1 = csr_w[beg + e + 1];
      float w2 = csr_w[beg + e + 2],   w3 = csr_w[beg + e + 3];
      f32x4 v0 = *(const f32x4*)(base + (size_t)s0 * 1024);
      f32x4 v1 = *(const f32x4*)(base + (size_t)s1 * 1024);
      f32x4 v2 = *(const f32x4*)(base + (size_t)s2 * 1024);
      f32x4 v3 = *(const f32x4*)(base + (size_t)s3 * 1024);
      a += w0 * v0 + w1 * v1 + w2 * v2 + w3 * v3;
    }
    for (; e < cnt; ++e) {
      int s = csr_src[beg + e];
      float w = csr_w[beg + e];
      a += w * *(const f32x4*)(base + (size_t)s * 1024);
    }
    {
      float di = dinv[d];
      a += (di * di) * *(const f32x4*)(base + (size_t)d * 1024);
    }
    float bj = gcnb[j];
    aggs[bh * 4 + 0][j] = a[0] + bj;
    aggs[bh * 4 + 1][j] = a[1] + bj;
    aggs[bh * 4 + 2][j] = a[2] + bj;
    aggs[bh * 4 + 3][j] = a[3] + bj;
  }
  __syncthreads();
  // MLP: thread (b = tid>>5, t = tid&31) owns hidden dims {t, t+32}
  const int b = tid >> 5;
  const int t = tid & 31;
  float acc1 = b1[t], acc2 = b1[t + 32];
#pragma unroll 8
  for (int kc = 0; kc < 32; ++kc) {
    float4 a  = *(const float4*)&aggs[b][kc * 4];
    float4 w1 = *(const float4*)&W1T[t][kc * 4];
    float4 w2 = *(const float4*)&W1T[t + 32][kc * 4];
    acc1 += a.x * w1.x + a.y * w1.y + a.z * w1.z + a.w * w1.w;
    acc2 += a.x * w2.x + a.y * w2.y + a.z * w2.z + a.w * w2.w;
  }
  float s1 = acc1 * frcp(1.f + fexp2(-1.44269504f * acc1));
  float s2 = acc2 * frcp(1.f + fexp2(-1.44269504f * acc2));
  float part = s1 * W2[t] + s2 * W2[t + 32];
#pragma unroll
  for (int msk = 16; msk >= 1; msk >>= 1) part += __shfl_xor(part, msk);
  if (t == 0) out[(size_t)b * NN_ + d] = part + b2[0];
}

extern "C" void kernel_launch(void* const* d_in, const int* in_sizes, int n_in,
                              void* d_out, int out_size, void* d_ws, size_t ws_size,
                              hipStream_t stream) {
  const float* x    = (const float*)d_in[0];
  const int*   ei   = (const int*)d_in[1];
  const float* Wih  = (const float*)d_in[2];
  const float* Whh  = (const float*)d_in[3];
  const float* bih  = (const float*)d_in[4];
  const float* bhh  = (const float*)d_in[5];
  const float* gcnW = (const float*)d_in[6];
  const float* gcnb = (const float*)d_in[7];
  const float* W1   = (const float*)d_in[8];
  const float* b1   = (const float*)d_in[9];
  const float* W2   = (const float*)d_in[10];
  const float* b2   = (const float*)d_in[11];
  float* out = (float*)d_out;
  char* ws = (char*)d_ws;

  _Float16* W16    = (_Float16*)(ws);                    // 163840
  _Float16* Wg16   = (_Float16*)(ws + 163840);           // 32768
  float*    bias   = (float*)(ws + 196608);              // 2048
  float*    xwT    = (float*)(ws + 198656);              // 8192000  [node][dim][batch]
  float*    deg    = (float*)(ws + 8390656);             // 8192
  float*    dinv   = (float*)(ws + 8398848);             // 8192
  int*      offs   = (int*)(ws + 8407040);               // 8192
  int*      cursor = (int*)(ws + 8415232);               // 8192
  int*      csrs   = (int*)(ws + 8423424);               // 128000
  float*    csrw   = (float*)(ws + 8551424);             // 128000

  prep_kernel<<<394, 256, 0, stream>>>(Wih, Whh, bih, bhh, gcnW, W16, Wg16, bias, deg);
  deg_kernel<<<133, 256, 0, stream>>>(ei, deg);
  scan_kernel<<<1, 1024, 0, stream>>>(deg, offs, cursor, dinv);
  fill_kernel<<<125, 256, 0, stream>>>(ei, dinv, cursor, csrs, csrw);
  lstm_gcn_kernel<<<500, 512, 0, stream>>>(x, W16, bias, Wg16, xwT);
  gathermlp_kernel<<<NN_, 256, 0, stream>>>(xwT, offs, deg, dinv, csrs, csrw,
                                            gcnb, W1, b1, W2, b2, out);
}

// Round 6
// 635.154 us; speedup vs baseline: 1.0463x; 1.0463x over previous
//
#include <hip/hip_runtime.h>

typedef _Float16 f16x8 __attribute__((ext_vector_type(8)));
typedef _Float16 f16x4 __attribute__((ext_vector_type(4)));
typedef _Float16 f16x2 __attribute__((ext_vector_type(2)));
typedef float f32x4 __attribute__((ext_vector_type(4)));

#define NB_   8
#define NN_   2000
#define TT_   64
#define FF_   32
#define HH_   128
#define EE_   32000
#define KD    160        // F + H
#define RSTR  192        // swizzled LDS row stride (f16 elems)
#define NODES 32         // nodes per block
#define BUFE  (NODES * RSTR)   // one activation buffer (elems)

__device__ __forceinline__ float fexp2(float v) { return __builtin_amdgcn_exp2f(v); }
__device__ __forceinline__ float frcp(float v)  { return __builtin_amdgcn_rcpf(v); }

// ---- prep: pack pre-scaled [Wih|Whh] -> fp16 [512][160], gcn_W^T -> fp16, bias, deg=0
// gate rows i,f,o: * -1.44269504 ; g rows [256,384): * -2.88539008
__global__ void prep_kernel(const float* __restrict__ Wih, const float* __restrict__ Whh,
                            const float* __restrict__ bih, const float* __restrict__ bhh,
                            const float* __restrict__ gcnW,
                            _Float16* __restrict__ W16, _Float16* __restrict__ Wg16,
                            float* __restrict__ bias, float* __restrict__ deg) {
  int idx = blockIdx.x * 256 + threadIdx.x;
  if (idx < 512 * KD) {
    int col = idx / KD, k = idx % KD;
    float v = (k < 32) ? Wih[col * 32 + k] : Whh[col * 128 + (k - 32)];
    float sc = (col >= 256 && col < 384) ? -2.88539008f : -1.44269504f;
    W16[idx] = (_Float16)(v * sc);
  } else if (idx < 512 * KD + 128 * 128) {
    int i2 = idx - 512 * KD;
    int colg = i2 >> 7, k = i2 & 127;
    Wg16[i2] = (_Float16)gcnW[k * 128 + colg];   // Wg16[c][k] = gcnW[k][c]
  } else if (idx < 512 * KD + 128 * 128 + 512) {
    int i3 = idx - (512 * KD + 128 * 128);
    float sc = (i3 >= 256 && i3 < 384) ? -2.88539008f : -1.44269504f;
    bias[i3] = (bih[i3] + bhh[i3]) * sc;
  } else if (idx < 512 * KD + 128 * 128 + 512 + NN_) {
    deg[idx - (512 * KD + 128 * 128 + 512)] = 0.f;
  }
}

__global__ void deg_kernel(const int* __restrict__ ei, float* __restrict__ deg) {
  int e = blockIdx.x * 256 + threadIdx.x;
  if (e < EE_ + NN_) {
    int d = (e < EE_) ? ei[EE_ + e] : (e - EE_);
    atomicAdd(&deg[d], 1.f);
  }
}

// ---- exclusive scan of (deg-1) + dinv, one block
__global__ void scan_kernel(const float* __restrict__ deg, int* __restrict__ offs,
                            int* __restrict__ cursor, float* __restrict__ dinv) {
  __shared__ int s0[2048], s1[2048];
  int t = threadIdx.x;
  for (int i = t; i < 2048; i += 1024) s0[i] = (i < NN_) ? ((int)deg[i] - 1) : 0;
  __syncthreads();
  int* src = s0; int* dst = s1;
  for (int off = 1; off < 2048; off <<= 1) {
    for (int i = t; i < 2048; i += 1024)
      dst[i] = src[i] + ((i >= off) ? src[i - off] : 0);
    __syncthreads();
    int* tmp = src; src = dst; dst = tmp;
  }
  for (int i = t; i < NN_; i += 1024) {
    int exc = src[i] - ((int)deg[i] - 1);
    offs[i] = exc;
    cursor[i] = exc;
    float d = deg[i];
    dinv[i] = (d > 0.f) ? __builtin_amdgcn_rsqf(d) : 0.f;
  }
}

__global__ void fill_kernel(const int* __restrict__ ei, const float* __restrict__ dinv,
                            int* __restrict__ cursor, int* __restrict__ csr_src,
                            float* __restrict__ csr_w) {
  int e = blockIdx.x * 256 + threadIdx.x;
  if (e >= EE_) return;
  int s = ei[e], d = ei[EE_ + e];
  int pos = atomicAdd(&cursor[d], 1);
  csr_src[pos] = s;
  csr_w[pos] = dinv[s] * dinv[d];
}

// ---- fused LSTM + GCN-GEMM. 500 blocks x 512 thr, 32 nodes/block.
// Double-buffered activation tile (XOR-swizzled): step t reads buf[t&1], gates write
// h(t+1)/x(t+1) to buf[(t+1)&1] -> ONE barrier per step. Weights + bias in regs;
// bias enters as the C operand of the kc=0 MFMA. Epilogue writes xw in [n][b][dim]
// with full-line float4 stores (r5's [n][dim][b] interleave caused cross-XCD
// false sharing: FETCH 67MB->1.17GB — never interleave blocks within a line).
__global__ __launch_bounds__(512, 4) void lstm_gcn_kernel(
    const float* __restrict__ x, const _Float16* __restrict__ W16,
    const float* __restrict__ bias, const _Float16* __restrict__ Wg16,
    float* __restrict__ xw) {
  __shared__ _Float16 A[2 * BUFE];          // 24576 B
  const int tid  = threadIdx.x;
  const int wave = tid >> 6;
  const int lane = tid & 63;
  const int n15  = lane & 15;
  const int q    = lane >> 4;
  const int m    = n15 & 7;
  const int hm   = m >> 2;
  const int qx   = q ^ (m & 3);
  const int node0 = blockIdx.x * NODES;

  // weight A-frags (rows = gate dims g*128+wave*16+n15), pre-scaled; bias f32
  f16x8 Af[4][5];
  f32x4 bt[4];
#pragma unroll
  for (int g = 0; g < 4; ++g) {
    const int row = g * 128 + wave * 16 + n15;
#pragma unroll
    for (int kc = 0; kc < 5; ++kc)
      Af[g][kc] = *(const f16x8*)(W16 + row * KD + kc * 32 + q * 8);
    bt[g] = *(const f32x4*)(bias + g * 128 + wave * 16 + q * 4);
  }

  // per-lane LDS offsets (XOR swizzle: elem(row,k) = row*192 + (((k>>3)^(row&7))<<3) + (k&7))
  const int bRow = n15 * RSTR + (qx << 3);   // + ((kc^hm)<<5) + nt*16*RSTR
  const int hOff = n15 * RSTR + (((4 + 2 * wave + (q >> 1)) ^ m) << 3) + ((q & 1) << 2);

  // x staging: thread stages 2 floats of one node-row per step
  const int xrow = tid >> 4;          // 0..31
  const int xf   = (tid & 15) * 2;
  const int xOff = xrow * RSTR + (((xf >> 3) ^ (xrow & 7)) << 3) + (xf & 7);
  const float* xb = x + (size_t)(node0 + xrow) * (TT_ * FF_) + xf;

  // buf0: h = 0, x(0)
  {
    int row = tid >> 4, ci = tid & 15;
    f16x8 z8 = {(_Float16)0, (_Float16)0, (_Float16)0, (_Float16)0,
                (_Float16)0, (_Float16)0, (_Float16)0, (_Float16)0};
    *(f16x8*)(A + row * RSTR + (((4 + ci) ^ (row & 7)) << 3)) = z8;
    float2 v = *(const float2*)xb;
    f16x2 p = {(_Float16)v.x, (_Float16)v.y};
    *(f16x2*)(A + xOff) = p;
  }
  __syncthreads();

  f32x4 c[2];
  c[0] = (f32x4){0, 0, 0, 0};
  c[1] = (f32x4){0, 0, 0, 0};

  for (int t = 0; t < TT_; ++t) {
    const _Float16* src = A + (t & 1) * BUFE;
    _Float16*       dst = A + ((t + 1) & 1) * BUFE;
    const bool more = (t + 1 < TT_);
    float2 xv;
    if (more) xv = *(const float2*)(xb + (t + 1) * FF_);

    // ---- MFMA phase: z = W·[x;h] + bias (bias via C operand on kc=0)
    f32x4 acc[2][4];
    {
      f16x8 bf0[2];
#pragma unroll
      for (int nt = 0; nt < 2; ++nt)
        bf0[nt] = *(const f16x8*)(src + nt * (16 * RSTR) + bRow + (hm << 5));
#pragma unroll
      for (int nt = 0; nt < 2; ++nt)
#pragma unroll
        for (int g = 0; g < 4; ++g)
          acc[nt][g] = __builtin_amdgcn_mfma_f32_16x16x32_f16(Af[g][0], bf0[nt], bt[g], 0, 0, 0);
#pragma unroll
      for (int kc = 1; kc < 5; ++kc)
#pragma unroll
        for (int nt = 0; nt < 2; ++nt) {
          f16x8 bf = *(const f16x8*)(src + nt * (16 * RSTR) + bRow + ((kc ^ hm) << 5));
#pragma unroll
          for (int g = 0; g < 4; ++g)
            acc[nt][g] = __builtin_amdgcn_mfma_f32_16x16x32_f16(Af[g][kc], bf, acc[nt][g], 0, 0, 0);
        }
    }

    // ---- gates phase: write h(t+1), x(t+1) to the OTHER buffer
#pragma unroll
    for (int nt = 0; nt < 2; ++nt) {
      f16x4 hp;
#pragma unroll
      for (int r = 0; r < 4; ++r) {
        float si = frcp(1.f + fexp2(acc[nt][0][r]));
        float sf = frcp(1.f + fexp2(acc[nt][1][r]));
        float tg = 2.f * frcp(1.f + fexp2(acc[nt][2][r])) - 1.f;
        float so = frcp(1.f + fexp2(acc[nt][3][r]));
        float cn = sf * c[nt][r] + si * tg;
        c[nt][r] = cn;
        float tc = 2.f * frcp(1.f + fexp2(-2.88539008f * cn)) - 1.f;
        hp[r] = (_Float16)(so * tc);
      }
      *(f16x4*)(dst + nt * (16 * RSTR) + hOff) = hp;
    }
    if (more) { f16x2 p = {(_Float16)xv.x, (_Float16)xv.y}; *(f16x2*)(dst + xOff) = p; }
    __syncthreads();
  }

  // ---- epilogue: h(T) in buf0. xw[(n*8+b)*128 + col] = (h @ gcnW)[node][col]
  f16x8 Ag[4];
#pragma unroll
  for (int kc = 0; kc < 4; ++kc)
    Ag[kc] = *(const f16x8*)(Wg16 + (wave * 16 + n15) * HH_ + kc * 32 + q * 8);
  f32x4 acc2[2];
  acc2[0] = (f32x4){0, 0, 0, 0};
  acc2[1] = (f32x4){0, 0, 0, 0};
#pragma unroll
  for (int kc = 0; kc < 4; ++kc)
#pragma unroll
    for (int nt = 0; nt < 2; ++nt) {
      f16x8 bf = *(const f16x8*)(A + nt * (16 * RSTR) + bRow + (((kc + 1) ^ hm) << 5));
      acc2[nt] = __builtin_amdgcn_mfma_f32_16x16x32_f16(Ag[kc], bf, acc2[nt], 0, 0, 0);
    }
#pragma unroll
  for (int nt = 0; nt < 2; ++nt) {
    int mnode = node0 + nt * 16 + n15;
    int b = mnode / NN_;
    int n = mnode - b * NN_;
    *(float4*)(xw + ((size_t)n * 8 + b) * HH_ + wave * 16 + q * 4) =
        (float4){acc2[nt][0], acc2[nt][1], acc2[nt][2], acc2[nt][3]};
  }
}

// ---- fused CSR gather + MLP head: block per dst, 512 thr; xw is [n][b][dim].
// Gather: thread = (dim j, batch-quad bq) -> 2 scalar loads/edge, 4-edge unroll.
// MLP: thread = (batch = wave, hidden t = lane); W1 in LDS un-transposed
// (lane t spans 0..63 -> 2-way bank access, free); full-wave shfl reduce.
__global__ __launch_bounds__(512) void gathermlp_kernel(
    const float* __restrict__ xw, const int* __restrict__ offs,
    const float* __restrict__ deg, const float* __restrict__ dinv,
    const int* __restrict__ csr_src, const float* __restrict__ csr_w,
    const float* __restrict__ gcnb,
    const float* __restrict__ W1, const float* __restrict__ b1,
    const float* __restrict__ W2, const float* __restrict__ b2,
    float* __restrict__ out) {
  __shared__ float aggs[8][128];
  __shared__ float W1s[128 * 64];           // 32 KB
  const int d = blockIdx.x;
  const int tid = threadIdx.x;
  {
    const float4* W1v = (const float4*)W1;
    float4* W1sv = (float4*)W1s;
    for (int i = tid; i < 2048; i += 512) W1sv[i] = W1v[i];
  }
  {
    const int j  = tid & 127;               // dim
    const int bq = tid >> 7;                // batch pair: batches 2bq, 2bq+1
    const int beg = offs[d];
    const int cnt = (int)deg[d] - 1;
    const float* base = xw + bq * 256 + j;  // + s*1024 ; [0]=batch 2bq, [128]=2bq+1
    float a0 = 0.f, a1 = 0.f;
    int e = 0;
    for (; e + 3 < cnt; e += 4) {
      int   s0 = csr_src[beg + e],     s1 = csr_src[beg + e + 1];
      int   s2 = csr_src[beg + e + 2], s3 = csr_src[beg + e + 3];
      float w0 = csr_w[beg + e],       w1 = csr_w[beg + e + 1];
      float w2 = csr_w[beg + e + 2],   w3 = csr_w[beg + e + 3];
      const float* p0 = base + (size_t)s0 * 1024;
      const float* p1 = base + (size_t)s1 * 1024;
      const float* p2 = base + (size_t)s2 * 1024;
      const float* p3 = base + (size_t)s3 * 1024;
      a0 += w0 * p0[0] + w1 * p1[0] + w2 * p2[0] + w3 * p3[0];
      a1 += w0 * p0[128] + w1 * p1[128] + w2 * p2[128] + w3 * p3[128];
    }
    for (; e < cnt; ++e) {
      int s = csr_src[beg + e];
      float w = csr_w[beg + e];
      const float* p = base + (size_t)s * 1024;
      a0 += w * p[0];
      a1 += w * p[128];
    }
    {
      float di = dinv[d];
      float w = di * di;
      const float* p = base + (size_t)d * 1024;
      a0 += w * p[0];
      a1 += w * p[128];
    }
    float bj = gcnb[j];
    aggs[2 * bq + 0][j] = a0 + bj;
    aggs[2 * bq + 1][j] = a1 + bj;
  }
  __syncthreads();
  // MLP: batch b = wave, hidden dim t = lane
  const int b = tid >> 6;
  const int t = tid & 63;
  float acc = b1[t];
#pragma unroll 8
  for (int k = 0; k < 128; ++k) acc += aggs[b][k] * W1s[k * 64 + t];
  float s = acc * frcp(1.f + fexp2(-1.44269504f * acc));
  float part = s * W2[t];
#pragma unroll
  for (int msk = 32; msk >= 1; msk >>= 1) part += __shfl_xor(part, msk);
  if (t == 0) out[(size_t)b * NN_ + d] = part + b2[0];
}

extern "C" void kernel_launch(void* const* d_in, const int* in_sizes, int n_in,
                              void* d_out, int out_size, void* d_ws, size_t ws_size,
                              hipStream_t stream) {
  const float* x    = (const float*)d_in[0];
  const int*   ei   = (const int*)d_in[1];
  const float* Wih  = (const float*)d_in[2];
  const float* Whh  = (const float*)d_in[3];
  const float* bih  = (const float*)d_in[4];
  const float* bhh  = (const float*)d_in[5];
  const float* gcnW = (const float*)d_in[6];
  const float* gcnb = (const float*)d_in[7];
  const float* W1   = (const float*)d_in[8];
  const float* b1   = (const float*)d_in[9];
  const float* W2   = (const float*)d_in[10];
  const float* b2   = (const float*)d_in[11];
  float* out = (float*)d_out;
  char* ws = (char*)d_ws;

  _Float16* W16    = (_Float16*)(ws);                    // 163840
  _Float16* Wg16   = (_Float16*)(ws + 163840);           // 32768
  float*    bias   = (float*)(ws + 196608);              // 2048
  float*    xw     = (float*)(ws + 198656);              // 8192000  [n][b][dim]
  float*    deg    = (float*)(ws + 8390656);             // 8192
  float*    dinv   = (float*)(ws + 8398848);             // 8192
  int*      offs   = (int*)(ws + 8407040);               // 8192
  int*      cursor = (int*)(ws + 8415232);               // 8192
  int*      csrs   = (int*)(ws + 8423424);               // 128000
  float*    csrw   = (float*)(ws + 8551424);             // 128000

  prep_kernel<<<394, 256, 0, stream>>>(Wih, Whh, bih, bhh, gcnW, W16, Wg16, bias, deg);
  deg_kernel<<<133, 256, 0, stream>>>(ei, deg);
  scan_kernel<<<1, 1024, 0, stream>>>(deg, offs, cursor, dinv);
  fill_kernel<<<125, 256, 0, stream>>>(ei, dinv, cursor, csrs, csrw);
  lstm_gcn_kernel<<<500, 512, 0, stream>>>(x, W16, bias, Wg16, xw);
  gathermlp_kernel<<<NN_, 512, 0, stream>>>(xw, offs, deg, dinv, csrs, csrw,
                                            gcnb, W1, b1, W2, b2, out);
}

// Round 7
// 424.933 us; speedup vs baseline: 1.5639x; 1.4947x over previous
//
#include <hip/hip_runtime.h>

typedef _Float16 f16x8 __attribute__((ext_vector_type(8)));
typedef _Float16 f16x4 __attribute__((ext_vector_type(4)));
typedef _Float16 f16x2 __attribute__((ext_vector_type(2)));
typedef float f32x4 __attribute__((ext_vector_type(4)));

#define NB_   8
#define NN_   2000
#define TT_   64
#define FF_   32
#define HH_   128
#define EE_   32000
#define KD    160        // F + H
#define RSTR  192        // swizzled LDS row stride (f16 elems)
#define NODES 64         // nodes per block
#define BUFE  (NODES * RSTR)   // one activation buffer (elems)

__device__ __forceinline__ float fexp2(float v) { return __builtin_amdgcn_exp2f(v); }
__device__ __forceinline__ float frcp(float v)  { return __builtin_amdgcn_rcpf(v); }

// ---- prep: pack pre-scaled [Wih|Whh] -> fp16 [512][160], gcn_W^T -> fp16, bias, deg=0
// gate rows i,f,o: * -1.44269504 ; g rows [256,384): * -2.88539008
__global__ void prep_kernel(const float* __restrict__ Wih, const float* __restrict__ Whh,
                            const float* __restrict__ bih, const float* __restrict__ bhh,
                            const float* __restrict__ gcnW,
                            _Float16* __restrict__ W16, _Float16* __restrict__ Wg16,
                            float* __restrict__ bias, float* __restrict__ deg) {
  int idx = blockIdx.x * 256 + threadIdx.x;
  if (idx < 512 * KD) {
    int col = idx / KD, k = idx % KD;
    float v = (k < 32) ? Wih[col * 32 + k] : Whh[col * 128 + (k - 32)];
    float sc = (col >= 256 && col < 384) ? -2.88539008f : -1.44269504f;
    W16[idx] = (_Float16)(v * sc);
  } else if (idx < 512 * KD + 128 * 128) {
    int i2 = idx - 512 * KD;
    int colg = i2 >> 7, k = i2 & 127;
    Wg16[i2] = (_Float16)gcnW[k * 128 + colg];   // Wg16[c][k] = gcnW[k][c]
  } else if (idx < 512 * KD + 128 * 128 + 512) {
    int i3 = idx - (512 * KD + 128 * 128);
    float sc = (i3 >= 256 && i3 < 384) ? -2.88539008f : -1.44269504f;
    bias[i3] = (bih[i3] + bhh[i3]) * sc;
  } else if (idx < 512 * KD + 128 * 128 + 512 + NN_) {
    deg[idx - (512 * KD + 128 * 128 + 512)] = 0.f;
  }
}

__global__ void deg_kernel(const int* __restrict__ ei, float* __restrict__ deg) {
  int e = blockIdx.x * 256 + threadIdx.x;
  if (e < EE_ + NN_) {
    int d = (e < EE_) ? ei[EE_ + e] : (e - EE_);
    atomicAdd(&deg[d], 1.f);
  }
}

// ---- exclusive scan of (deg-1) + dinv, one block
__global__ void scan_kernel(const float* __restrict__ deg, int* __restrict__ offs,
                            int* __restrict__ cursor, float* __restrict__ dinv) {
  __shared__ int s0[2048], s1[2048];
  int t = threadIdx.x;
  for (int i = t; i < 2048; i += 1024) s0[i] = (i < NN_) ? ((int)deg[i] - 1) : 0;
  __syncthreads();
  int* src = s0; int* dst = s1;
  for (int off = 1; off < 2048; off <<= 1) {
    for (int i = t; i < 2048; i += 1024)
      dst[i] = src[i] + ((i >= off) ? src[i - off] : 0);
    __syncthreads();
    int* tmp = src; src = dst; dst = tmp;
  }
  for (int i = t; i < NN_; i += 1024) {
    int exc = src[i] - ((int)deg[i] - 1);
    offs[i] = exc;
    cursor[i] = exc;
    float d = deg[i];
    dinv[i] = (d > 0.f) ? __builtin_amdgcn_rsqf(d) : 0.f;
  }
}

__global__ void fill_kernel(const int* __restrict__ ei, const float* __restrict__ dinv,
                            int* __restrict__ cursor, int* __restrict__ csr_src,
                            float* __restrict__ csr_w) {
  int e = blockIdx.x * 256 + threadIdx.x;
  if (e >= EE_) return;
  int s = ei[e], d = ei[EE_ + e];
  int pos = atomicAdd(&cursor[d], 1);
  csr_src[pos] = s;
  csr_w[pos] = dinv[s] * dinv[d];
}

// ---- fused LSTM + GCN-GEMM. 250 blocks x 512 thr, 64 nodes/block, 1 block/CU.
// __launch_bounds__(512,2) -> 256-reg combined VGPR/AGPR budget: weights (80) + bias
// (16) + c (16) + acc (64, AGPR) all register-resident with NO scratch spill
// (r5/r6 lesson: (512,4)'s 128-reg budget spilled the weights -> 1 GB of scratch
// traffic, FETCH 67MB->1.08GB). Double-buffered swizzled activation tile: one
// barrier per step. Bias enters as C operand of the kc=0 MFMA.
__global__ __launch_bounds__(512, 2) void lstm_gcn_kernel(
    const float* __restrict__ x, const _Float16* __restrict__ W16,
    const float* __restrict__ bias, const _Float16* __restrict__ Wg16,
    float* __restrict__ xw) {
  __shared__ _Float16 A[2 * BUFE];          // 49152 B
  const int tid  = threadIdx.x;
  const int wave = tid >> 6;
  const int lane = tid & 63;
  const int n15  = lane & 15;
  const int q    = lane >> 4;
  const int m    = n15 & 7;
  const int hm   = m >> 2;
  const int qx   = q ^ (m & 3);
  const int node0 = blockIdx.x * NODES;

  // weight A-frags (rows = gate dims g*128+wave*16+n15), pre-scaled; bias f32
  f16x8 Af[4][5];
  f32x4 bt[4];
#pragma unroll
  for (int g = 0; g < 4; ++g) {
    const int row = g * 128 + wave * 16 + n15;
#pragma unroll
    for (int kc = 0; kc < 5; ++kc)
      Af[g][kc] = *(const f16x8*)(W16 + row * KD + kc * 32 + q * 8);
    bt[g] = *(const f32x4*)(bias + g * 128 + wave * 16 + q * 4);
  }

  // per-lane LDS offsets (XOR swizzle: elem(row,k) = row*192 + (((k>>3)^(row&7))<<3) + (k&7))
  const int bRow = n15 * RSTR + (qx << 3);   // + ((kc^hm)<<5) + nt*16*RSTR
  const int hOff = n15 * RSTR + (((4 + 2 * wave + (q >> 1)) ^ m) << 3) + ((q & 1) << 2);

  // x staging: thread stages 4 floats (float4) of one node-row per step
  const int xrow = tid >> 3;          // 0..63
  const int xf   = (tid & 7) * 4;
  const int xOff = xrow * RSTR + (((xf >> 3) ^ (xrow & 7)) << 3) + (xf & 7);
  const float* xb = x + (size_t)(node0 + xrow) * (TT_ * FF_) + xf;

  // buf0: h = 0, x(0)
  for (int i = tid; i < 1024; i += 512) {
    int row = i >> 4, ci = i & 15;
    f16x8 z8 = {(_Float16)0, (_Float16)0, (_Float16)0, (_Float16)0,
                (_Float16)0, (_Float16)0, (_Float16)0, (_Float16)0};
    *(f16x8*)(A + row * RSTR + (((4 + ci) ^ (row & 7)) << 3)) = z8;
  }
  {
    float4 v = *(const float4*)xb;
    f16x4 p = {(_Float16)v.x, (_Float16)v.y, (_Float16)v.z, (_Float16)v.w};
    *(f16x4*)(A + xOff) = p;
  }
  __syncthreads();

  f32x4 c[4];
#pragma unroll
  for (int nt = 0; nt < 4; ++nt) c[nt] = (f32x4){0, 0, 0, 0};

  for (int t = 0; t < TT_; ++t) {
    const _Float16* srcb = A + (t & 1) * BUFE;
    _Float16*       dstb = A + ((t + 1) & 1) * BUFE;
    const bool more = (t + 1 < TT_);
    float4 xv;
    if (more) xv = *(const float4*)(xb + (t + 1) * FF_);

    // ---- MFMA phase: z = W·[x;h] + bias (bias via C operand on kc=0)
    f32x4 acc[4][4];
#pragma unroll
    for (int nt = 0; nt < 4; ++nt) {
      f16x8 bf0 = *(const f16x8*)(srcb + nt * (16 * RSTR) + bRow + (hm << 5));
#pragma unroll
      for (int g = 0; g < 4; ++g)
        acc[nt][g] = __builtin_amdgcn_mfma_f32_16x16x32_f16(Af[g][0], bf0, bt[g], 0, 0, 0);
    }
#pragma unroll
    for (int kc = 1; kc < 5; ++kc)
#pragma unroll
      for (int nt = 0; nt < 4; ++nt) {
        f16x8 bf = *(const f16x8*)(srcb + nt * (16 * RSTR) + bRow + ((kc ^ hm) << 5));
#pragma unroll
        for (int g = 0; g < 4; ++g)
          acc[nt][g] = __builtin_amdgcn_mfma_f32_16x16x32_f16(Af[g][kc], bf, acc[nt][g], 0, 0, 0);
      }

    // ---- gates phase: write h(t+1), x(t+1) to the OTHER buffer
#pragma unroll
    for (int nt = 0; nt < 4; ++nt) {
      f16x4 hp;
#pragma unroll
      for (int r = 0; r < 4; ++r) {
        float si = frcp(1.f + fexp2(acc[nt][0][r]));
        float sf = frcp(1.f + fexp2(acc[nt][1][r]));
        float tg = 2.f * frcp(1.f + fexp2(acc[nt][2][r])) - 1.f;
        float so = frcp(1.f + fexp2(acc[nt][3][r]));
        float cn = sf * c[nt][r] + si * tg;
        c[nt][r] = cn;
        float tc = 2.f * frcp(1.f + fexp2(-2.88539008f * cn)) - 1.f;
        hp[r] = (_Float16)(so * tc);
      }
      *(f16x4*)(dstb + nt * (16 * RSTR) + hOff) = hp;
    }
    if (more) {
      f16x4 p = {(_Float16)xv.x, (_Float16)xv.y, (_Float16)xv.z, (_Float16)xv.w};
      *(f16x4*)(dstb + xOff) = p;
    }
    __syncthreads();
  }

  // ---- epilogue: h(T) in buf0. xw[(n*8+b)*128 + col] = (h @ gcnW)[node][col]
  f16x8 Ag[4];
#pragma unroll
  for (int kc = 0; kc < 4; ++kc)
    Ag[kc] = *(const f16x8*)(Wg16 + (wave * 16 + n15) * HH_ + kc * 32 + q * 8);
  f32x4 acc2[4];
#pragma unroll
  for (int nt = 0; nt < 4; ++nt) acc2[nt] = (f32x4){0, 0, 0, 0};
#pragma unroll
  for (int kc = 0; kc < 4; ++kc)
#pragma unroll
    for (int nt = 0; nt < 4; ++nt) {
      f16x8 bf = *(const f16x8*)(A + nt * (16 * RSTR) + bRow + (((kc + 1) ^ hm) << 5));
      acc2[nt] = __builtin_amdgcn_mfma_f32_16x16x32_f16(Ag[kc], bf, acc2[nt], 0, 0, 0);
    }
#pragma unroll
  for (int nt = 0; nt < 4; ++nt) {
    int mnode = node0 + nt * 16 + n15;
    int b = mnode / NN_;
    int n = mnode - b * NN_;
    *(float4*)(xw + ((size_t)n * 8 + b) * HH_ + wave * 16 + q * 4) =
        (float4){acc2[nt][0], acc2[nt][1], acc2[nt][2], acc2[nt][3]};
  }
}

// ---- fused CSR gather + MLP head: block per dst, 512 thr; xw is [n][b][dim].
// Gather: thread = (dim j, batch-pair bq) -> 2 scalar loads/edge, 4-edge unroll.
// MLP: thread = (batch = wave, hidden t = lane); W1 read directly from global
// (coalesced 256B lines, L1-hot across blocks — no LDS staging needed).
__global__ __launch_bounds__(512) void gathermlp_kernel(
    const float* __restrict__ xw, const int* __restrict__ offs,
    const float* __restrict__ deg, const float* __restrict__ dinv,
    const int* __restrict__ csr_src, const float* __restrict__ csr_w,
    const float* __restrict__ gcnb,
    const float* __restrict__ W1, const float* __restrict__ b1,
    const float* __restrict__ W2, const float* __restrict__ b2,
    float* __restrict__ out) {
  __shared__ float aggs[8][128];
  const int d = blockIdx.x;
  const int tid = threadIdx.x;
  {
    const int j  = tid & 127;               // dim
    const int bq = tid >> 7;                // batch pair: batches 2bq, 2bq+1
    const int beg = offs[d];
    const int cnt = (int)deg[d] - 1;
    const float* base = xw + bq * 256 + j;  // + s*1024 ; [0]=batch 2bq, [128]=2bq+1
    float a0 = 0.f, a1 = 0.f;
    int e = 0;
    for (; e + 3 < cnt; e += 4) {
      int   s0 = csr_src[beg + e],     s1 = csr_src[beg + e + 1];
      int   s2 = csr_src[beg + e + 2], s3 = csr_src[beg + e + 3];
      float w0 = csr_w[beg + e],       w1 = csr_w[beg + e + 1];
      float w2 = csr_w[beg + e + 2],   w3 = csr_w[beg + e + 3];
      const float* p0 = base + (size_t)s0 * 1024;
      const float* p1 = base + (size_t)s1 * 1024;
      const float* p2 = base + (size_t)s2 * 1024;
      const float* p3 = base + (size_t)s3 * 1024;
      a0 += w0 * p0[0] + w1 * p1[0] + w2 * p2[0] + w3 * p3[0];
      a1 += w0 * p0[128] + w1 * p1[128] + w2 * p2[128] + w3 * p3[128];
    }
    for (; e < cnt; ++e) {
      int s = csr_src[beg + e];
      float w = csr_w[beg + e];
      const float* p = base + (size_t)s * 1024;
      a0 += w * p[0];
      a1 += w * p[128];
    }
    {
      float di = dinv[d];
      float w = di * di;
      const float* p = base + (size_t)d * 1024;
      a0 += w * p[0];
      a1 += w * p[128];
    }
    float bj = gcnb[j];
    aggs[2 * bq + 0][j] = a0 + bj;
    aggs[2 * bq + 1][j] = a1 + bj;
  }
  __syncthreads();
  // MLP: batch b = wave, hidden dim t = lane
  const int b = tid >> 6;
  const int t = tid & 63;
  float acc = b1[t];
#pragma unroll 4
  for (int k = 0; k < 128; ++k) acc += aggs[b][k] * W1[k * 64 + t];
  float s = acc * frcp(1.f + fexp2(-1.44269504f * acc));
  float part = s * W2[t];
#pragma unroll
  for (int msk = 32; msk >= 1; msk >>= 1) part += __shfl_xor(part, msk);
  if (t == 0) out[(size_t)b * NN_ + d] = part + b2[0];
}

extern "C" void kernel_launch(void* const* d_in, const int* in_sizes, int n_in,
                              void* d_out, int out_size, void* d_ws, size_t ws_size,
                              hipStream_t stream) {
  const float* x    = (const float*)d_in[0];
  const int*   ei   = (const int*)d_in[1];
  const float* Wih  = (const float*)d_in[2];
  const float* Whh  = (const float*)d_in[3];
  const float* bih  = (const float*)d_in[4];
  const float* bhh  = (const float*)d_in[5];
  const float* gcnW = (const float*)d_in[6];
  const float* gcnb = (const float*)d_in[7];
  const float* W1   = (const float*)d_in[8];
  const float* b1   = (const float*)d_in[9];
  const float* W2   = (const float*)d_in[10];
  const float* b2   = (const float*)d_in[11];
  float* out = (float*)d_out;
  char* ws = (char*)d_ws;

  _Float16* W16    = (_Float16*)(ws);                    // 163840
  _Float16* Wg16   = (_Float16*)(ws + 163840);           // 32768
  float*    bias   = (float*)(ws + 196608);              // 2048
  float*    xw     = (float*)(ws + 198656);              // 8192000  [n][b][dim]
  float*    deg    = (float*)(ws + 8390656);             // 8192
  float*    dinv   = (float*)(ws + 8398848);             // 8192
  int*      offs   = (int*)(ws + 8407040);               // 8192
  int*      cursor = (int*)(ws + 8415232);               // 8192
  int*      csrs   = (int*)(ws + 8423424);               // 128000
  float*    csrw   = (float*)(ws + 8551424);             // 128000

  prep_kernel<<<394, 256, 0, stream>>>(Wih, Whh, bih, bhh, gcnW, W16, Wg16, bias, deg);
  deg_kernel<<<133, 256, 0, stream>>>(ei, deg);
  scan_kernel<<<1, 1024, 0, stream>>>(deg, offs, cursor, dinv);
  fill_kernel<<<125, 256, 0, stream>>>(ei, dinv, cursor, csrs, csrw);
  lstm_gcn_kernel<<<250, 512, 0, stream>>>(x, W16, bias, Wg16, xw);
  gathermlp_kernel<<<NN_, 512, 0, stream>>>(xw, offs, deg, dinv, csrs, csrw,
                                            gcnb, W1, b1, W2, b2, out);
}